// Round 8
// baseline (200.170 us; speedup 1.0000x reference)
//
#include <hip/hip_runtime.h>

#define N_NODES 50000
#define N_EDGES 800000
#define N_FEAT 128
#define N_HID 128
#define N_CLS 40
#define BN_EPS 1e-5f

#define CSR_STRIDE 64   // padded CSR row stride; max degree ~40 (Poisson 16)
#define NXCD 8
#define P_NODES 6250    // nodes per XCD partition (50000/8)
#define CSR_B 1024      // CSR-build blocks: 128 per partition
#define CSR_BO 128      // blocks per partition
#define WPACK_B 84
#define XPACK_B 3125

typedef short bf16x8 __attribute__((ext_vector_type(8)));
typedef float f32x4 __attribute__((ext_vector_type(4)));
typedef int i32x4 __attribute__((ext_vector_type(4)));      // nt-compatible int4
typedef unsigned u32x4 __attribute__((ext_vector_type(4))); // nt-compatible uint4

// RNE float->bf16 helpers
__device__ __forceinline__ unsigned bfpack(float a, float b) {
    unsigned ua = __float_as_uint(a), ub = __float_as_uint(b);
    ua = (ua + 0x7FFFu + ((ua >> 16) & 1u)) >> 16;
    ub = (ub + 0x7FFFu + ((ub >> 16) & 1u)) >> 16;
    return ua | (ub << 16);
}
__device__ __forceinline__ unsigned short bfr1(float a) {
    unsigned u = __float_as_uint(a);
    u = (u + 0x7FFFu + ((u >> 16) & 1u)) >> 16;
    return (unsigned short)u;
}
__device__ __forceinline__ float bflo(unsigned u) { return __uint_as_float(u << 16); }
__device__ __forceinline__ float bfhi(unsigned u) { return __uint_as_float(u & 0xFFFF0000u); }

// ---------------------------------------------------------------------------
// Fused CSR-build + prep, XCD-partitioned + NON-TEMPORAL streaming.
// CSR blocks [0,1024): partition p = b&7 (round-robin block->XCD), 128 blocks
// per partition scan the full edge list and keep edges with dst in-range.
// All streaming traffic (edge reads, x fp32 reads, x_bf16 writes) is issued
// nt (L2-bypass) so the ONLY L2 working set is csr_pad+deg_i (~825 KB/XCD,
// fits 4 MB) -> each csr line written back exactly once. r6 counters showed
// ~23 MB write-amp + 38 MB fetch from the x-pack stream thrashing
// partially-filled csr lines out of L2; nt removes the thrash.
// ---------------------------------------------------------------------------
__global__ __launch_bounds__(256) void degprep_kernel(
    const int* __restrict__ src, const int* __restrict__ dst,
    int* __restrict__ deg_i, unsigned short* __restrict__ csr_pad,
    const float* __restrict__ W1l, const float* __restrict__ W1r,
    const float* __restrict__ W2l, const float* __restrict__ W2r,
    const float* __restrict__ x, unsigned* __restrict__ WfA,
    unsigned* __restrict__ WfB, unsigned* __restrict__ x_bf16) {
    int b = blockIdx.x;
    int t = threadIdx.x;
    if (b < CSR_B) {
        const int p = b & (NXCD - 1);
        const int bo = b >> 3;
        const int plo = p * P_NODES;
        const int phi = plo + P_NODES;
        const i32x4* dst4 = (const i32x4*)dst;
        const i32x4* src4 = (const i32x4*)src;
        for (int base = bo * 1024; base < N_EDGES; base += CSR_BO * 1024) {
            int e = base + t * 4;
            if (e < N_EDGES) {
                i32x4 d4 = __builtin_nontemporal_load(&dst4[e >> 2]);
                i32x4 s4 = __builtin_nontemporal_load(&src4[e >> 2]);
#pragma unroll
                for (int q = 0; q < 4; ++q) {
                    int dq = d4[q];
                    if (dq >= plo && dq < phi) {
                        int r = atomicAdd(&deg_i[dq], 1);
                        if (r < CSR_STRIDE)
                            csr_pad[dq * CSR_STRIDE + r] = (unsigned short)s4[q];
                    }
                }
            }
        }
        return;
    }
    int i = (b - CSR_B) * 256 + t;
    if (b < CSR_B + WPACK_B) {
        if (i < 16384) {
            int f = i >> 8, r = i & 255;
            int lane = r >> 2, u = r & 3;
            int phase = f >> 5, kc = (f >> 3) & 3, nt = f & 7;
            int k0 = phase * 128 + kc * 32 + (lane >> 4) * 8 + u * 2;
            int n = nt * 16 + (lane & 15);
            float w0, w1;
            if (k0 < 128) {
                w0 = W1l[n * 128 + k0];
                w1 = W1l[n * 128 + k0 + 1];
            } else {
                w0 = W1r[n * 128 + k0 - 128];
                w1 = W1r[n * 128 + k0 - 127];
            }
            WfA[i] = bfpack(w0, w1);
        } else if (i < 21504) {
            int j = i - 16384;
            int f = j >> 8, r = j & 255;
            int lane = r >> 2, u = r & 3;
            int kc = f / 5, nt = f % 5;
            int k0 = kc * 32 + (lane >> 4) * 8 + u * 2;
            int n = nt * 16 + (lane & 15);
            float w0, w1;
            if (n < 40) {
                w0 = W2l[n * 128 + k0];
                w1 = W2l[n * 128 + k0 + 1];
            } else {
                w0 = W2r[(n - 40) * 128 + k0];
                w1 = W2r[(n - 40) * 128 + k0 + 1];
            }
            WfB[j] = bfpack(w0, w1);
        }
    } else {
        int j = (b - CSR_B - WPACK_B) * 256 + t;
        if (j < 800000) {
            const f32x4* xf = (const f32x4*)x;
            f32x4 a = __builtin_nontemporal_load(&xf[(size_t)j * 2]);
            f32x4 bq = __builtin_nontemporal_load(&xf[(size_t)j * 2 + 1]);
            u32x4 o;
            o.x = bfpack(a.x, a.y);
            o.y = bfpack(a.z, a.w);
            o.z = bfpack(bq.x, bq.y);
            o.w = bfpack(bq.z, bq.w);
            __builtin_nontemporal_store(o, &((u32x4*)x_bf16)[j]);
        }
    }
}

// ---------------------------------------------------------------------------
// Gather-mean layer 1 (bf16 x): subgroup-per-node, shuffle-free, ILP-8.
// 16 lanes own a node; padded-CSR addressing (beg = gid*64, n = deg).
// ---------------------------------------------------------------------------
__global__ __launch_bounds__(256) void gather1_kernel(const unsigned short* __restrict__ csr_pad,
                                                      const int* __restrict__ deg_i,
                                                      const unsigned* __restrict__ x_bf16,
                                                      unsigned* __restrict__ agg1b) {
    int sg = threadIdx.x >> 4;
    int li = threadIdx.x & 15;
    int gid = blockIdx.x * 16 + sg;
    if (gid >= N_NODES) return;
    int n = min(deg_i[gid], CSR_STRIDE);
    int beg = gid * CSR_STRIDE;
    int end = beg + n;
    const uint4* xb = (const uint4*)x_bf16;
    float acc[8];
#pragma unroll
    for (int j = 0; j < 8; ++j) acc[j] = 0.f;

    int e = beg;
    for (; e + 7 < end; e += 8) {
        uint4 tv[8];
#pragma unroll
        for (int q = 0; q < 8; ++q) {
            int s = csr_pad[e + q];
            tv[q] = xb[(size_t)s * 16 + li];
        }
#pragma unroll
        for (int q = 0; q < 8; ++q) {
            acc[0] += bflo(tv[q].x); acc[1] += bfhi(tv[q].x);
            acc[2] += bflo(tv[q].y); acc[3] += bfhi(tv[q].y);
            acc[4] += bflo(tv[q].z); acc[5] += bfhi(tv[q].z);
            acc[6] += bflo(tv[q].w); acc[7] += bfhi(tv[q].w);
        }
    }
    if (e + 3 < end) {
        uint4 tv[4];
#pragma unroll
        for (int q = 0; q < 4; ++q) {
            int s = csr_pad[e + q];
            tv[q] = xb[(size_t)s * 16 + li];
        }
#pragma unroll
        for (int q = 0; q < 4; ++q) {
            acc[0] += bflo(tv[q].x); acc[1] += bfhi(tv[q].x);
            acc[2] += bflo(tv[q].y); acc[3] += bfhi(tv[q].y);
            acc[4] += bflo(tv[q].z); acc[5] += bfhi(tv[q].z);
            acc[6] += bflo(tv[q].w); acc[7] += bfhi(tv[q].w);
        }
        e += 4;
    }
    for (; e < end; ++e) {
        int s = csr_pad[e];
        uint4 t0 = xb[(size_t)s * 16 + li];
        acc[0] += bflo(t0.x); acc[1] += bfhi(t0.x);
        acc[2] += bflo(t0.y); acc[3] += bfhi(t0.y);
        acc[4] += bflo(t0.z); acc[5] += bfhi(t0.z);
        acc[6] += bflo(t0.w); acc[7] += bfhi(t0.w);
    }
    float inv = 1.0f / fmaxf((float)n, 1.0f);
    uint4 o;
    o.x = bfpack(acc[0] * inv, acc[1] * inv);
    o.y = bfpack(acc[2] * inv, acc[3] * inv);
    o.z = bfpack(acc[4] * inv, acc[5] * inv);
    o.w = bfpack(acc[6] * inv, acc[7] * inv);
    ((uint4*)agg1b)[(size_t)gid * 16 + li] = o;
}

// ---------------------------------------------------------------------------
// Fused GEMM1+GEMM2 via MFMA (bf16):
//   h = BN(ReLU(agg1 @ W1l^T + b1 + x @ W1r^T)) kept in LDS;
//   [z2 | p2] = h @ [W2l^T | W2r^T].
// ---------------------------------------------------------------------------
__global__ __launch_bounds__(256) void gemm_fused_kernel(
    const unsigned* __restrict__ agg1b, const unsigned* __restrict__ xb,
    const unsigned* __restrict__ WfA, const unsigned* __restrict__ WfB,
    const float* __restrict__ b1,
    const float* __restrict__ gamma, const float* __restrict__ beta,
    const float* __restrict__ rmean, const float* __restrict__ rvar,
    unsigned short* __restrict__ z2s, float* __restrict__ p2) {
    __shared__ unsigned Asu[64 * 68];
    const int t = threadIdx.x;
    const int wid = __builtin_amdgcn_readfirstlane(t >> 6);
    const int lane = t & 63;
    const int li = lane & 15;
    const int quad = lane >> 4;
    const int mbase = blockIdx.x * 64;

    f32x4 dacc[8];
#pragma unroll
    for (int nt = 0; nt < 8; ++nt) dacc[nt] = (f32x4){0.f, 0.f, 0.f, 0.f};

    for (int phase = 0; phase < 2; ++phase) {
        const unsigned* __restrict__ A = phase ? xb : agg1b;
        __syncthreads();
#pragma unroll
        for (int i = 0; i < 4; ++i) {
            int e = i * 256 + t;
            int row = e >> 4, seg = e & 15;
            int rr = mbase + row;
            rr = (rr < N_NODES) ? rr : N_NODES - 1;
            uint4 v = ((const uint4*)A)[(size_t)rr * 16 + seg];
            *(uint4*)&Asu[row * 68 + seg * 4] = v;
        }
        __syncthreads();
        bf16x8 af[4];
#pragma unroll
        for (int kc = 0; kc < 4; ++kc)
            af[kc] = *(const bf16x8*)&Asu[(wid * 16 + li) * 68 + kc * 16 + quad * 4];

        const unsigned* __restrict__ Wp = WfA + phase * 8192;
#pragma unroll
        for (int nt = 0; nt < 8; ++nt) {
#pragma unroll
            for (int kc = 0; kc < 4; ++kc) {
                bf16x8 bfr = *(const bf16x8*)(Wp + (size_t)(kc * 8 + nt) * 256 + lane * 4);
                dacc[nt] = __builtin_amdgcn_mfma_f32_16x16x32_bf16(af[kc], bfr, dacc[nt], 0, 0, 0);
            }
        }
    }

    // --- GEMM1 epilogue: bias + ReLU + BN, h (bf16) into LDS -------------
    __syncthreads();
    unsigned short* Hs = (unsigned short*)Asu;  // row stride 136 ushorts
#pragma unroll
    for (int nt = 0; nt < 8; ++nt) {
        int cg = nt * 16 + li;
        float sc = gamma[cg] * rsqrtf(rvar[cg] + BN_EPS);
        float sh = fmaf(-rmean[cg], sc, beta[cg]);
        float bb = b1[cg];
#pragma unroll
        for (int r = 0; r < 4; ++r) {
            int row = wid * 16 + quad * 4 + r;
            float pre = dacc[nt][r] + bb;
            Hs[row * 136 + cg] = bfr1(fmaf(fmaxf(pre, 0.f), sc, sh));
        }
    }
    __syncthreads();

    // --- GEMM2 -----------------------------------------------------------
    bf16x8 af2[4];
#pragma unroll
    for (int kc = 0; kc < 4; ++kc)
        af2[kc] = *(const bf16x8*)&Asu[(wid * 16 + li) * 68 + kc * 16 + quad * 4];

    f32x4 d2[5];
#pragma unroll
    for (int nt = 0; nt < 5; ++nt) d2[nt] = (f32x4){0.f, 0.f, 0.f, 0.f};
#pragma unroll
    for (int nt = 0; nt < 5; ++nt) {
#pragma unroll
        for (int kc = 0; kc < 4; ++kc) {
            bf16x8 bfr = *(const bf16x8*)(WfB + (size_t)(kc * 5 + nt) * 256 + lane * 4);
            d2[nt] = __builtin_amdgcn_mfma_f32_16x16x32_bf16(af2[kc], bfr, d2[nt], 0, 0, 0);
        }
    }

#pragma unroll
    for (int nt = 0; nt < 5; ++nt) {
        int cg = nt * 16 + li;
#pragma unroll
        for (int r = 0; r < 4; ++r) {
            int row = mbase + wid * 16 + quad * 4 + r;
            if (row < N_NODES) {
                float vv = d2[nt][r];
                if (cg < 40) z2s[(size_t)row * 40 + cg] = bfr1(vv);
                else p2[(size_t)row * 40 + (cg - 40)] = vv;
            }
        }
    }
}

// ---------------------------------------------------------------------------
// Gather layer 2 + final (bf16 z2): subgroup-per-node, shuffle-free, ILP-8.
// 10 lanes own a node; padded-CSR addressing.
// ---------------------------------------------------------------------------
__global__ __launch_bounds__(256) void gather2_kernel(const unsigned short* __restrict__ csr_pad,
                                                      const int* __restrict__ deg_i,
                                                      const unsigned short* __restrict__ z2s,
                                                      const float* __restrict__ p2,
                                                      const float* __restrict__ b2,
                                                      float* __restrict__ out) {
    int t = threadIdx.x;
    int sub = t / 10;
    int li = t - sub * 10;
    if (sub >= 25) return;
    int gid = blockIdx.x * 25 + sub;
    if (gid >= N_NODES) return;
    int n = min(deg_i[gid], CSR_STRIDE);
    int beg = gid * CSR_STRIDE;
    int end = beg + n;
    const uint2* z2 = (const uint2*)z2s;
    float4 acc = {0.f, 0.f, 0.f, 0.f};
    int e = beg;
    for (; e + 7 < end; e += 8) {
        uint2 tv[8];
#pragma unroll
        for (int q = 0; q < 8; ++q) {
            int s = csr_pad[e + q];
            tv[q] = z2[(size_t)s * 10 + li];
        }
#pragma unroll
        for (int q = 0; q < 8; ++q) {
            acc.x += bflo(tv[q].x); acc.y += bfhi(tv[q].x);
            acc.z += bflo(tv[q].y); acc.w += bfhi(tv[q].y);
        }
    }
    if (e + 3 < end) {
        uint2 tv[4];
#pragma unroll
        for (int q = 0; q < 4; ++q) {
            int s = csr_pad[e + q];
            tv[q] = z2[(size_t)s * 10 + li];
        }
#pragma unroll
        for (int q = 0; q < 4; ++q) {
            acc.x += bflo(tv[q].x); acc.y += bfhi(tv[q].x);
            acc.z += bflo(tv[q].y); acc.w += bfhi(tv[q].y);
        }
        e += 4;
    }
    for (; e < end; ++e) {
        int s = csr_pad[e];
        uint2 t0 = z2[(size_t)s * 10 + li];
        acc.x += bflo(t0.x); acc.y += bfhi(t0.x);
        acc.z += bflo(t0.y); acc.w += bfhi(t0.y);
    }
    float inv = 1.0f / fmaxf((float)n, 1.0f);
    float4 p = ((const float4*)p2)[(size_t)gid * 10 + li];
    float4 bb = ((const float4*)b2)[li];
    float4 r;
    r.x = fmaf(acc.x, inv, p.x + bb.x);
    r.y = fmaf(acc.y, inv, p.y + bb.y);
    r.z = fmaf(acc.z, inv, p.z + bb.z);
    r.w = fmaf(acc.w, inv, p.w + bb.w);
    ((float4*)out)[(size_t)gid * 10 + li] = r;
}

// ---------------------------------------------------------------------------
// Launch: 5 dispatches. ws layout (int units):
//   deg_i[50048] (memset 0)
//   csr_pad ushort[50000*64] = 1,600,000 ints
//   WfA u32[16384], WfB u32[5120]
//   x_bf16 u32[3200000]
//   agg1b u32[50048*64]
//   z2s ushort[50048*40] + p2 f32[50048*40]
// ---------------------------------------------------------------------------
extern "C" void kernel_launch(void* const* d_in, const int* in_sizes, int n_in,
                              void* d_out, int out_size, void* d_ws, size_t ws_size,
                              hipStream_t stream) {
    const float* x     = (const float*)d_in[0];
    const int*   ei    = (const int*)d_in[1];
    const float* W1l   = (const float*)d_in[2];
    const float* b1    = (const float*)d_in[3];
    const float* W1r   = (const float*)d_in[4];
    const float* gamma = (const float*)d_in[5];
    const float* beta  = (const float*)d_in[6];
    const float* rmean = (const float*)d_in[7];
    const float* rvar  = (const float*)d_in[8];
    const float* W2l   = (const float*)d_in[9];
    const float* b2    = (const float*)d_in[10];
    const float* W2r   = (const float*)d_in[11];
    float* out = (float*)d_out;

    int* deg_i              = (int*)d_ws;
    unsigned short* csr_pad = (unsigned short*)(deg_i + 50048);
    unsigned* WfA           = (unsigned*)(deg_i + 50048 + 1600000);
    unsigned* WfB           = WfA + 16384;
    unsigned* x_bf16        = WfB + 5120;
    unsigned* agg1b         = x_bf16 + 3200000;
    unsigned short* z2s     = (unsigned short*)(agg1b + (size_t)50048 * 64);
    float* p2               = (float*)(z2s + (size_t)50048 * 40);

    const int* src = ei;
    const int* dst = ei + N_EDGES;

    hipMemsetAsync(deg_i, 0, (size_t)50048 * sizeof(int), stream);

    degprep_kernel<<<CSR_B + WPACK_B + XPACK_B, 256, 0, stream>>>(
        src, dst, deg_i, csr_pad, W1l, W1r, W2l, W2r, x, WfA, WfB, x_bf16);

    gather1_kernel<<<(N_NODES + 15) / 16, 256, 0, stream>>>(csr_pad, deg_i, x_bf16, agg1b);

    gemm_fused_kernel<<<(N_NODES + 63) / 64, 256, 0, stream>>>(
        agg1b, x_bf16, WfA, WfB, b1, gamma, beta, rmean, rvar, z2s, p2);

    gather2_kernel<<<(N_NODES + 24) / 25, 256, 0, stream>>>(csr_pad, deg_i, z2s, p2, b2, out);
}